// Round 1
// baseline (281.964 us; speedup 1.0000x reference)
//
#include <hip/hip_runtime.h>
#include <math.h>

// Problem constants (B=4, H=8, P=196, D=64, NF=8, S=5)
#define BHP 6272   // B*H*P
#define PPX 196
#define NS  5
#define NFX 8
#define DDX 64

// ---------------------------------------------------------------------------
// K1: per 8 rows r: y5[r, s*64+d] = dot(x[r,:], W[s*64+d,:]) + b[s*64+d]
//     base[r, s*64+d] = dot(silu(y5[r,s,:]), BW[d,:])
// ---------------------------------------------------------------------------
__global__ __launch_bounds__(256) void k1_lin_base(
    const float* __restrict__ x, const float* __restrict__ W,
    const float* __restrict__ bias, const float* __restrict__ BW,
    float* __restrict__ y5, float* __restrict__ basef)
{
  __shared__ float xs[8][64];
  __shared__ float sy[8][320];
  const int r0 = blockIdx.x * 8;
  const int t = threadIdx.x;
  for (int idx = t; idx < 8 * 64; idx += 256)
    xs[idx >> 6][idx & 63] = x[(size_t)(r0 + (idx >> 6)) * 64 + (idx & 63)];
  __syncthreads();
  for (int o = t; o < 320; o += 256) {
    const float* wrow = W + o * 64;
    float acc[8];
#pragma unroll
    for (int rr = 0; rr < 8; ++rr) acc[rr] = 0.f;
    for (int c = 0; c < 64; c += 4) {
      const float4 w4 = *reinterpret_cast<const float4*>(wrow + c);
#pragma unroll
      for (int rr = 0; rr < 8; ++rr)
        acc[rr] += xs[rr][c] * w4.x + xs[rr][c + 1] * w4.y +
                   xs[rr][c + 2] * w4.z + xs[rr][c + 3] * w4.w;
    }
    const float bb = bias[o];
#pragma unroll
    for (int rr = 0; rr < 8; ++rr) {
      const float y = acc[rr] + bb;
      y5[(size_t)(r0 + rr) * 320 + o] = y;
      sy[rr][o] = y / (1.f + __expf(-y));   // silu
    }
  }
  __syncthreads();
  for (int o = t; o < 320; o += 256) {
    const int s = o >> 6, d = o & 63;
    const float* brow = BW + d * 64;
    float acc[8];
#pragma unroll
    for (int rr = 0; rr < 8; ++rr) acc[rr] = 0.f;
    for (int c = 0; c < 64; c += 4) {
      const float4 w4 = *reinterpret_cast<const float4*>(brow + c);
#pragma unroll
      for (int rr = 0; rr < 8; ++rr)
        acc[rr] += sy[rr][s * 64 + c] * w4.x + sy[rr][s * 64 + c + 1] * w4.y +
                   sy[rr][s * 64 + c + 2] * w4.z + sy[rr][s * 64 + c + 3] * w4.w;
    }
#pragma unroll
    for (int rr = 0; rr < 8; ++rr)
      basef[(size_t)(r0 + rr) * 320 + o] = acc[rr];
  }
}

// ---------------------------------------------------------------------------
// K2: one wave per (bh, s2, p2); lane = d.
//   f_q[b,h,s2,p2,d] = sum_{f2<8} sin(grid[s,f]*y5[bh*196+p, s, d]) * coef[d,f,s]
//     with j=(s2*8+f2)*196+p2 ; p=j/40 ; s=(j%40)/8 ; f=j%8   (raw-reshape remap)
//   base at (p'=i0/5, s'=i0%5), i0 = s2*196+p2
//   a[bh,s2,p2] = sum_d sigmoid(f*ssp + base*sbase)
// ---------------------------------------------------------------------------
__global__ __launch_bounds__(256) void k2_act(
    const float* __restrict__ y5, const float* __restrict__ basef,
    const float* __restrict__ grid, const float* __restrict__ coef,
    const float* __restrict__ ssp, const float* __restrict__ sbase,
    float* __restrict__ a)
{
  const int lane = threadIdx.x & 63;
  const int wave = threadIdx.x >> 6;
  const int idx = blockIdx.x * 4 + wave;        // [0, 31360)
  const int p2 = idx % 196;
  const int s2 = (idx / 196) % 5;
  const int bh = idx / 980;
  const int h = bh & 7;
  const int d = lane;
  const int i0 = s2 * 196 + p2;
  const float basev =
      basef[(size_t)(bh * 196 + i0 / 5) * 320 + (i0 % 5) * 64 + d];
  float fv = 0.f;
#pragma unroll
  for (int f2 = 0; f2 < 8; ++f2) {
    const int j = (s2 * 8 + f2) * 196 + p2;
    const int p = j / 40;
    const int m = j % 40;            // = s*8 + f
    const int s = m >> 3;
    const float g = grid[m];         // grid[s][f]
    const float qv = y5[(size_t)(bh * 196 + p) * 320 + s * 64 + d];
    const float cf = coef[(d * 8 + (m & 7)) * 5 + s];
    fv += sinf(g * qv) * cf;
  }
  const int so = ((h * 5 + s2) * 196 + p2) * 64 + d;
  const float v = fv * ssp[so] + basev * sbase[so];
  float sg = 1.f / (1.f + __expf(-v));
#pragma unroll
  for (int off = 32; off > 0; off >>= 1) sg += __shfl_xor(sg, off);
  if (lane == 0) a[idx] = sg;
}

// ---------------------------------------------------------------------------
// K3: one block per (bh, i) output row; thread j < 196.
//   f[j] = sum_s cqo[s,i,j] * sum_f sin(grid[s,f]*(aq[s,i]+ak[s,j])) * cqk[(i*196+j)*40 + f*5 + s]
//   out = softmax_j(f)
// ---------------------------------------------------------------------------
__global__ __launch_bounds__(256) void k3_outer(
    const float* __restrict__ aq, const float* __restrict__ ak,
    const float* __restrict__ grid, const float* __restrict__ cqk,
    const float* __restrict__ cqo, float* __restrict__ out)
{
  const int row = blockIdx.x;           // [0, 6272)
  const int bh = row / 196, i = row % 196;
  const int t = threadIdx.x;
  __shared__ float gs[40];
  __shared__ float aqs[5];
  __shared__ float redm[4], reds[4];
  if (t < 40) gs[t] = grid[t];
  if (t < 5) aqs[t] = aq[bh * 980 + t * 196 + i];
  __syncthreads();

  float fval = -INFINITY;
  const int j = t;
  if (j < 196) {
    const float* cp = cqk + (size_t)(i * 196 + j) * 40;
    float cf[40];
#pragma unroll
    for (int u = 0; u < 10; ++u) {
      const float4 v4 = reinterpret_cast<const float4*>(cp)[u];
      cf[u * 4 + 0] = v4.x; cf[u * 4 + 1] = v4.y;
      cf[u * 4 + 2] = v4.z; cf[u * 4 + 3] = v4.w;
    }
    float fj = 0.f;
#pragma unroll
    for (int s = 0; s < 5; ++s) {
      const float qk = aqs[s] + ak[bh * 980 + s * 196 + j];
      float a0 = 0.f;
#pragma unroll
      for (int f = 0; f < 8; ++f)
        a0 += sinf(gs[s * 8 + f] * qk) * cf[f * 5 + s];
      fj += a0 * cqo[(s * 196 + i) * 196 + j];
    }
    fval = fj;
  }
  // block-wide max
  float m = fval;
#pragma unroll
  for (int off = 32; off > 0; off >>= 1) m = fmaxf(m, __shfl_xor(m, off));
  if ((t & 63) == 0) redm[t >> 6] = m;
  __syncthreads();
  m = fmaxf(fmaxf(redm[0], redm[1]), fmaxf(redm[2], redm[3]));
  const float e = (j < 196) ? __expf(fval - m) : 0.f;
  float ssum = e;
#pragma unroll
  for (int off = 32; off > 0; off >>= 1) ssum += __shfl_xor(ssum, off);
  if ((t & 63) == 0) reds[t >> 6] = ssum;
  __syncthreads();
  const float tot = reds[0] + reds[1] + reds[2] + reds[3];
  if (j < 196) out[(size_t)row * 196 + j] = e / tot;
}

// ---------------------------------------------------------------------------
extern "C" void kernel_launch(void* const* d_in, const int* in_sizes, int n_in,
                              void* d_out, int out_size, void* d_ws, size_t ws_size,
                              hipStream_t stream) {
  const float* q          = (const float*)d_in[0];
  const float* k          = (const float*)d_in[1];
  // d_in[2] = scale (unused, as in reference)
  const float* grid       = (const float*)d_in[3];
  const float* grid_outer = (const float*)d_in[4];
  const float* base_w     = (const float*)d_in[5];
  const float* coef_q     = (const float*)d_in[6];
  const float* coef_k     = (const float*)d_in[7];
  const float* coef_qk    = (const float*)d_in[8];
  const float* scale_base = (const float*)d_in[9];
  const float* scale_sp   = (const float*)d_in[10];
  const float* cqo        = (const float*)d_in[11];
  const float* lqw        = (const float*)d_in[12];
  const float* lqb        = (const float*)d_in[13];
  const float* lkw        = (const float*)d_in[14];
  const float* lkb        = (const float*)d_in[15];
  float* out = (float*)d_out;

  float* q5 = (float*)d_ws;                 // [6272,320]
  float* k5 = q5 + (size_t)BHP * 320;       // [6272,320]
  float* bq = k5 + (size_t)BHP * 320;       // [6272,320]
  float* bk = bq + (size_t)BHP * 320;       // [6272,320]
  float* aq = bk + (size_t)BHP * 320;       // [32,5,196]
  float* ak = aq + 32 * 5 * 196;            // [32,5,196]

  k1_lin_base<<<dim3(BHP / 8), dim3(256), 0, stream>>>(q, lqw, lqb, base_w, q5, bq);
  k1_lin_base<<<dim3(BHP / 8), dim3(256), 0, stream>>>(k, lkw, lkb, base_w, k5, bk);
  k2_act<<<dim3(31360 / 4), dim3(256), 0, stream>>>(q5, bq, grid, coef_q,
                                                    scale_sp, scale_base, aq);
  k2_act<<<dim3(31360 / 4), dim3(256), 0, stream>>>(k5, bk, grid, coef_k,
                                                    scale_sp, scale_base, ak);
  k3_outer<<<dim3(BHP), dim3(256), 0, stream>>>(aq, ak, grid_outer, coef_qk,
                                                cqo, out);
}

// Round 2
// 183.347 us; speedup vs baseline: 1.5379x; 1.5379x over previous
//
#include <hip/hip_runtime.h>
#include <math.h>

// Problem constants (B=4, H=8, P=196, D=64, NF=8, S=5)
#define BHP 6272   // B*H*P

// ---------------------------------------------------------------------------
// K1: 16 rows per block, 320 threads (thread = output column o in [0,320)).
//   y5[r,o] = dot(x[r,:], W[o,:]) + b[o];  base[r, s*64+d] = dot(silu(y5[r,s,:]), BW[d,:])
// ---------------------------------------------------------------------------
__global__ __launch_bounds__(320) void k1_lin_base(
    const float* __restrict__ x, const float* __restrict__ W,
    const float* __restrict__ bias, const float* __restrict__ BW,
    float* __restrict__ y5, float* __restrict__ basef)
{
  __shared__ float xs[16][64];    // 4 KB
  __shared__ float sy[16][320];   // 20 KB
  const int r0 = blockIdx.x * 16;
  const int t = threadIdx.x;
  for (int idx = t; idx < 16 * 64; idx += 320)
    xs[idx >> 6][idx & 63] = x[(size_t)(r0 + (idx >> 6)) * 64 + (idx & 63)];
  __syncthreads();

  const int o = t;                 // exactly one output column per thread
  {
    const float* wrow = W + o * 64;
    float acc[16];
#pragma unroll
    for (int rr = 0; rr < 16; ++rr) acc[rr] = 0.f;
    for (int c = 0; c < 64; c += 4) {
      const float4 w4 = *reinterpret_cast<const float4*>(wrow + c);
#pragma unroll
      for (int rr = 0; rr < 16; ++rr) {
        const float4 x4 = *reinterpret_cast<const float4*>(&xs[rr][c]);
        acc[rr] += x4.x * w4.x + x4.y * w4.y + x4.z * w4.z + x4.w * w4.w;
      }
    }
    const float bb = bias[o];
#pragma unroll
    for (int rr = 0; rr < 16; ++rr) {
      const float y = acc[rr] + bb;
      y5[(size_t)(r0 + rr) * 320 + o] = y;
      sy[rr][o] = y / (1.f + __expf(-y));   // silu
    }
  }
  __syncthreads();
  {
    const int s = o >> 6, d = o & 63;
    const float* brow = BW + d * 64;
    float acc[16];
#pragma unroll
    for (int rr = 0; rr < 16; ++rr) acc[rr] = 0.f;
    for (int c = 0; c < 64; c += 4) {
      const float4 w4 = *reinterpret_cast<const float4*>(brow + c);
#pragma unroll
      for (int rr = 0; rr < 16; ++rr) {
        const float4 x4 = *reinterpret_cast<const float4*>(&sy[rr][s * 64 + c]);
        acc[rr] += x4.x * w4.x + x4.y * w4.y + x4.z * w4.z + x4.w * w4.w;
      }
    }
#pragma unroll
    for (int rr = 0; rr < 16; ++rr)
      basef[(size_t)(r0 + rr) * 320 + o] = acc[rr];
  }
}

// ---------------------------------------------------------------------------
// K2: one wave per (bh, s2, p2); lane = d.   (unchanged, accurate sinf)
// ---------------------------------------------------------------------------
__global__ __launch_bounds__(256) void k2_act(
    const float* __restrict__ y5, const float* __restrict__ basef,
    const float* __restrict__ grid, const float* __restrict__ coef,
    const float* __restrict__ ssp, const float* __restrict__ sbase,
    float* __restrict__ a)
{
  const int lane = threadIdx.x & 63;
  const int wave = threadIdx.x >> 6;
  const int idx = blockIdx.x * 4 + wave;        // [0, 31360)
  const int p2 = idx % 196;
  const int s2 = (idx / 196) % 5;
  const int bh = idx / 980;
  const int h = bh & 7;
  const int d = lane;
  const int i0 = s2 * 196 + p2;
  const float basev =
      basef[(size_t)(bh * 196 + i0 / 5) * 320 + (i0 % 5) * 64 + d];
  float fv = 0.f;
#pragma unroll
  for (int f2 = 0; f2 < 8; ++f2) {
    const int j = (s2 * 8 + f2) * 196 + p2;
    const int p = j / 40;
    const int m = j % 40;            // = s*8 + f
    const int s = m >> 3;
    const float g = grid[m];         // grid[s][f]
    const float qv = y5[(size_t)(bh * 196 + p) * 320 + s * 64 + d];
    const float cf = coef[(d * 8 + (m & 7)) * 5 + s];
    fv += sinf(g * qv) * cf;
  }
  const int so = ((h * 5 + s2) * 196 + p2) * 64 + d;
  const float v = fv * ssp[so] + basev * sbase[so];
  float sg = 1.f / (1.f + __expf(-v));
#pragma unroll
  for (int off = 32; off > 0; off >>= 1) sg += __shfl_xor(sg, off);
  if (lane == 0) a[idx] = sg;
}

// ---------------------------------------------------------------------------
// K2b: sin/cos tables for the outer basis.
//   tab[bh*7840 + m*196 + p] = {sin(g[m]*a[bh,s,p]), cos(g[m]*a[bh,s,p])}, m=s*8+f
// ---------------------------------------------------------------------------
__global__ __launch_bounds__(256) void k2b_tab(
    const float* __restrict__ aq, const float* __restrict__ ak,
    const float* __restrict__ go, float2* __restrict__ tq,
    float2* __restrict__ tk)
{
  const int n = blockIdx.x * 256 + threadIdx.x;   // [0, 250880)
  const int p = n % 196;
  const int m = (n / 196) % 40;
  const int bh = n / 7840;
  const int s = m >> 3;
  const float g = go[m];
  const int aidx = bh * 980 + s * 196 + p;
  float sv, cv;
  sincosf(g * aq[aidx], &sv, &cv);
  tq[n] = make_float2(sv, cv);
  sincosf(g * ak[aidx], &sv, &cv);
  tk[n] = make_float2(sv, cv);
}

// ---------------------------------------------------------------------------
// K3: block = (i, bh-group of 8). Pure-FMA inner loop via angle-addition:
//   sin(g(aq+ak)) = sin(g aq)cos(g ak) + cos(g aq)sin(g ak)
// ---------------------------------------------------------------------------
__global__ __launch_bounds__(256) void k3_outer(
    const float2* __restrict__ tq, const float2* __restrict__ tk,
    const float* __restrict__ cqk, const float* __restrict__ cqo,
    float* __restrict__ out)
{
  const int bx = blockIdx.x;            // [0, 784)
  const int i = bx >> 2;
  const int bh0 = (bx & 3) * 8;
  const int t = threadIdx.x;
  const int j = t;
  const bool act = j < 196;
  __shared__ float2 sqs[40];
  __shared__ float redm[4], reds[4];

  float cf[40];
  float cqo5[5];
  if (act) {
    const float4* cp =
        reinterpret_cast<const float4*>(cqk + (size_t)(i * 196 + j) * 40);
#pragma unroll
    for (int u = 0; u < 10; ++u) {
      const float4 v = cp[u];
      cf[4 * u + 0] = v.x; cf[4 * u + 1] = v.y;
      cf[4 * u + 2] = v.z; cf[4 * u + 3] = v.w;
    }
#pragma unroll
    for (int s = 0; s < 5; ++s) cqo5[s] = cqo[(s * 196 + i) * 196 + j];
  }

  for (int bi = 0; bi < 8; ++bi) {
    const int bh = bh0 + bi;
    __syncthreads();
    if (t < 40) sqs[t] = tq[bh * 7840 + t * 196 + i];
    __syncthreads();

    float fval = -INFINITY;
    if (act) {
      const float2* tkp = tk + bh * 7840 + j;
      float fj = 0.f;
#pragma unroll
      for (int s = 0; s < 5; ++s) {
        float t0 = 0.f;
#pragma unroll
        for (int f = 0; f < 8; ++f) {
          const int m = s * 8 + f;
          const float2 tkv = tkp[m * 196];
          const float2 sv = sqs[m];
          const float u = sv.x * tkv.y + sv.y * tkv.x;
          t0 = fmaf(u, cf[f * 5 + s], t0);
        }
        fj = fmaf(t0, cqo5[s], fj);
      }
      fval = fj;
    }
    // softmax over j within the block
    float mx = fval;
#pragma unroll
    for (int off = 32; off > 0; off >>= 1) mx = fmaxf(mx, __shfl_xor(mx, off));
    if ((t & 63) == 0) redm[t >> 6] = mx;
    __syncthreads();
    mx = fmaxf(fmaxf(redm[0], redm[1]), fmaxf(redm[2], redm[3]));
    const float e = act ? __expf(fval - mx) : 0.f;
    float ss = e;
#pragma unroll
    for (int off = 32; off > 0; off >>= 1) ss += __shfl_xor(ss, off);
    if ((t & 63) == 0) reds[t >> 6] = ss;
    __syncthreads();
    const float tot = reds[0] + reds[1] + reds[2] + reds[3];
    if (act) out[((size_t)(bh * 196 + i)) * 196 + j] = e / tot;
  }
}

// ---------------------------------------------------------------------------
extern "C" void kernel_launch(void* const* d_in, const int* in_sizes, int n_in,
                              void* d_out, int out_size, void* d_ws, size_t ws_size,
                              hipStream_t stream) {
  const float* q          = (const float*)d_in[0];
  const float* k          = (const float*)d_in[1];
  const float* grid       = (const float*)d_in[3];
  const float* grid_outer = (const float*)d_in[4];
  const float* base_w     = (const float*)d_in[5];
  const float* coef_q     = (const float*)d_in[6];
  const float* coef_k     = (const float*)d_in[7];
  const float* coef_qk    = (const float*)d_in[8];
  const float* scale_base = (const float*)d_in[9];
  const float* scale_sp   = (const float*)d_in[10];
  const float* cqo        = (const float*)d_in[11];
  const float* lqw        = (const float*)d_in[12];
  const float* lqb        = (const float*)d_in[13];
  const float* lkw        = (const float*)d_in[14];
  const float* lkb        = (const float*)d_in[15];
  float* out = (float*)d_out;

  float* q5 = (float*)d_ws;                 // [6272,320]
  float* k5 = q5 + (size_t)BHP * 320;       // [6272,320]
  float* bq = k5 + (size_t)BHP * 320;       // [6272,320]  (reused as tabq)
  float* bk = bq + (size_t)BHP * 320;       // [6272,320]  (reused as tabk)
  float* aq = bk + (size_t)BHP * 320;       // [32,5,196]
  float* ak = aq + 32 * 5 * 196;            // [32,5,196]
  float2* tabq = (float2*)bq;               // [32*40*196] float2 (4MB < 8MB)
  float2* tabk = (float2*)bk;

  k1_lin_base<<<dim3(BHP / 16), dim3(320), 0, stream>>>(q, lqw, lqb, base_w, q5, bq);
  k1_lin_base<<<dim3(BHP / 16), dim3(320), 0, stream>>>(k, lkw, lkb, base_w, k5, bk);
  k2_act<<<dim3(31360 / 4), dim3(256), 0, stream>>>(q5, bq, grid, coef_q,
                                                    scale_sp, scale_base, aq);
  k2_act<<<dim3(31360 / 4), dim3(256), 0, stream>>>(k5, bk, grid, coef_k,
                                                    scale_sp, scale_base, ak);
  k2b_tab<<<dim3(980), dim3(256), 0, stream>>>(aq, ak, grid_outer, tabq, tabk);
  k3_outer<<<dim3(784), dim3(256), 0, stream>>>(tabq, tabk, coef_qk, cqo, out);
}

// Round 3
// 160.629 us; speedup vs baseline: 1.7554x; 1.1414x over previous
//
#include <hip/hip_runtime.h>
#include <math.h>

// Problem constants (B=4, H=8, P=196, D=64, NF=8, S=5)
#define BHP 6272   // B*H*P

// ---------------------------------------------------------------------------
// K1 (q and k merged): 16 rows per block, 320 threads (thread = output col o).
//   y5[r,o] = dot(x[r,:], W[o,:]) + b[o];  base[r,s*64+d] = dot(silu(y5[r,s,:]), BW[d,:])
// ---------------------------------------------------------------------------
__global__ __launch_bounds__(320) void k1_lin_base(
    const float* __restrict__ qx, const float* __restrict__ kx,
    const float* __restrict__ Wq, const float* __restrict__ bq_,
    const float* __restrict__ Wk, const float* __restrict__ bk_,
    const float* __restrict__ BW,
    float* __restrict__ y5q, float* __restrict__ y5k,
    float* __restrict__ baseq, float* __restrict__ basek)
{
  const bool kside = blockIdx.x >= (BHP / 16);
  const float* x = kside ? kx : qx;
  const float* W = kside ? Wk : Wq;
  const float* bias = kside ? bk_ : bq_;
  float* y5 = kside ? y5k : y5q;
  float* basef = kside ? basek : baseq;
  const int r0 = (kside ? blockIdx.x - BHP / 16 : blockIdx.x) * 16;

  __shared__ float xs[16][64];    // 4 KB
  __shared__ float sy[16][320];   // 20 KB
  const int t = threadIdx.x;
  for (int idx = t; idx < 16 * 64; idx += 320)
    xs[idx >> 6][idx & 63] = x[(size_t)(r0 + (idx >> 6)) * 64 + (idx & 63)];
  __syncthreads();

  const int o = t;
  {
    const float* wrow = W + o * 64;
    float acc[16];
#pragma unroll
    for (int rr = 0; rr < 16; ++rr) acc[rr] = 0.f;
    for (int c = 0; c < 64; c += 4) {
      const float4 w4 = *reinterpret_cast<const float4*>(wrow + c);
#pragma unroll
      for (int rr = 0; rr < 16; ++rr) {
        const float4 x4 = *reinterpret_cast<const float4*>(&xs[rr][c]);
        acc[rr] += x4.x * w4.x + x4.y * w4.y + x4.z * w4.z + x4.w * w4.w;
      }
    }
    const float bb = bias[o];
#pragma unroll
    for (int rr = 0; rr < 16; ++rr) {
      const float y = acc[rr] + bb;
      y5[(size_t)(r0 + rr) * 320 + o] = y;
      sy[rr][o] = y / (1.f + __expf(-y));   // silu
    }
  }
  __syncthreads();
  {
    const int s = o >> 6, d = o & 63;
    const float* brow = BW + d * 64;
    float acc[16];
#pragma unroll
    for (int rr = 0; rr < 16; ++rr) acc[rr] = 0.f;
    for (int c = 0; c < 64; c += 4) {
      const float4 w4 = *reinterpret_cast<const float4*>(brow + c);
#pragma unroll
      for (int rr = 0; rr < 16; ++rr) {
        const float4 x4 = *reinterpret_cast<const float4*>(&sy[rr][s * 64 + c]);
        acc[rr] += x4.x * w4.x + x4.y * w4.y + x4.z * w4.z + x4.w * w4.w;
      }
    }
#pragma unroll
    for (int rr = 0; rr < 16; ++rr)
      basef[(size_t)(r0 + rr) * 320 + o] = acc[rr];
  }
}

// ---------------------------------------------------------------------------
// K2 (q and k merged): one wave per (side, bh, s2, p2); lane = d.
//   Uses HW __sinf (args <= ~120 rad -> fract error ~1e-5, feeds sigmoid: safe)
// ---------------------------------------------------------------------------
__global__ __launch_bounds__(256) void k2_act(
    const float* __restrict__ y5q, const float* __restrict__ bq,
    const float* __restrict__ y5k, const float* __restrict__ bk,
    const float* __restrict__ grid, const float* __restrict__ cq,
    const float* __restrict__ ck,
    const float* __restrict__ ssp, const float* __restrict__ sbase,
    float* __restrict__ aq, float* __restrict__ ak)
{
  const int lane = threadIdx.x & 63;
  const int wave = threadIdx.x >> 6;
  const int gi = blockIdx.x * 4 + wave;        // [0, 62720)
  const bool kside = gi >= 31360;
  const int idx = kside ? gi - 31360 : gi;
  const float* y5 = kside ? y5k : y5q;
  const float* basef = kside ? bk : bq;
  const float* coef = kside ? ck : cq;
  float* a = kside ? ak : aq;

  const int p2 = idx % 196;
  const int s2 = (idx / 196) % 5;
  const int bh = idx / 980;
  const int h = bh & 7;
  const int d = lane;
  const int i0 = s2 * 196 + p2;
  const float basev =
      basef[(size_t)(bh * 196 + i0 / 5) * 320 + (i0 % 5) * 64 + d];
  float fv = 0.f;
#pragma unroll
  for (int f2 = 0; f2 < 8; ++f2) {
    const int j = (s2 * 8 + f2) * 196 + p2;
    const int p = j / 40;
    const int m = j % 40;            // = s*8 + f
    const int s = m >> 3;
    const float g = grid[m];
    const float qv = y5[(size_t)(bh * 196 + p) * 320 + s * 64 + d];
    const float cf = coef[(d * 8 + (m & 7)) * 5 + s];
    fv += __sinf(g * qv) * cf;
  }
  const int so = ((h * 5 + s2) * 196 + p2) * 64 + d;
  const float v = fv * ssp[so] + basev * sbase[so];
  float sg = 1.f / (1.f + __expf(-v));
#pragma unroll
  for (int off = 32; off > 0; off >>= 1) sg += __shfl_xor(sg, off);
  if (lane == 0) a[idx] = sg;
}

// ---------------------------------------------------------------------------
// K2b: sin/cos tables (accurate sincosf; args up to ~1300 rad).
//   tab[bh*7840 + m*196 + p] = {sin(g[m]*a[bh,s,p]), cos(...)}, m = s*8+f
// ---------------------------------------------------------------------------
__global__ __launch_bounds__(256) void k2b_tab(
    const float* __restrict__ aq, const float* __restrict__ ak,
    const float* __restrict__ go, float2* __restrict__ tq,
    float2* __restrict__ tk)
{
  const int n = blockIdx.x * 256 + threadIdx.x;   // [0, 250880)
  const int p = n % 196;
  const int m = (n / 196) % 40;
  const int bh = n / 7840;
  const int s = m >> 3;
  const float g = go[m];
  const int aidx = bh * 980 + s * 196 + p;
  float sv, cv;
  sincosf(g * aq[aidx], &sv, &cv);
  tq[n] = make_float2(sv, cv);
  sincosf(g * ak[aidx], &sv, &cv);
  tk[n] = make_float2(sv, cv);
}

// ---------------------------------------------------------------------------
// K3: block = (bh, i-tile of 7). Thread j keeps its 40 tk float2 in REGISTERS
// (loaded once, reused over 7 rows); tq broadcast via LDS; cf streamed float4.
//   sin(g(aq+ak)) = sin(g aq)cos(g ak) + cos(g aq)sin(g ak)
// ---------------------------------------------------------------------------
__global__ __launch_bounds__(256) void k3_outer(
    const float2* __restrict__ tq, const float2* __restrict__ tk,
    const float* __restrict__ cqk, const float* __restrict__ cqo,
    float* __restrict__ out)
{
  const int bh = blockIdx.x / 28;
  const int it0 = (blockIdx.x % 28) * 7;
  const int t = threadIdx.x;
  const int j = t;
  const bool act = j < 196;
  __shared__ float2 sqs[40];
  __shared__ float redm[4], reds[4];

  float2 tkv[40];
  if (act) {
    const float2* tkp = tk + bh * 7840 + j;
#pragma unroll
    for (int m = 0; m < 40; ++m) tkv[m] = tkp[m * 196];
  }

  for (int ii = 0; ii < 7; ++ii) {
    const int i = it0 + ii;
    __syncthreads();
    if (t < 40) sqs[t] = tq[bh * 7840 + t * 196 + i];
    __syncthreads();

    float fval = -INFINITY;
    if (act) {
      float cf[40];
      const float4* cp =
          reinterpret_cast<const float4*>(cqk + (size_t)(i * 196 + j) * 40);
#pragma unroll
      for (int u = 0; u < 10; ++u) {
        const float4 v = cp[u];
        cf[4 * u + 0] = v.x; cf[4 * u + 1] = v.y;
        cf[4 * u + 2] = v.z; cf[4 * u + 3] = v.w;
      }
      float fj = 0.f;
#pragma unroll
      for (int s = 0; s < 5; ++s) {
        float t0 = 0.f;
#pragma unroll
        for (int f = 0; f < 8; ++f) {
          const int m = s * 8 + f;
          const float2 kv = tkv[m];
          const float2 sv = sqs[m];
          t0 = fmaf(sv.x * kv.y + sv.y * kv.x, cf[f * 5 + s], t0);
        }
        fj = fmaf(t0, cqo[(s * 196 + i) * 196 + j], fj);
      }
      fval = fj;
    }
    // softmax over j within the block
    float mx = fval;
#pragma unroll
    for (int off = 32; off > 0; off >>= 1) mx = fmaxf(mx, __shfl_xor(mx, off));
    if ((t & 63) == 0) redm[t >> 6] = mx;
    __syncthreads();
    mx = fmaxf(fmaxf(redm[0], redm[1]), fmaxf(redm[2], redm[3]));
    const float e = act ? __expf(fval - mx) : 0.f;
    float ss = e;
#pragma unroll
    for (int off = 32; off > 0; off >>= 1) ss += __shfl_xor(ss, off);
    if ((t & 63) == 0) reds[t >> 6] = ss;
    __syncthreads();
    const float tot = reds[0] + reds[1] + reds[2] + reds[3];
    if (act) out[((size_t)(bh * 196 + i)) * 196 + j] = e / tot;
  }
}

// ---------------------------------------------------------------------------
extern "C" void kernel_launch(void* const* d_in, const int* in_sizes, int n_in,
                              void* d_out, int out_size, void* d_ws, size_t ws_size,
                              hipStream_t stream) {
  const float* q          = (const float*)d_in[0];
  const float* k          = (const float*)d_in[1];
  const float* grid       = (const float*)d_in[3];
  const float* grid_outer = (const float*)d_in[4];
  const float* base_w     = (const float*)d_in[5];
  const float* coef_q     = (const float*)d_in[6];
  const float* coef_k     = (const float*)d_in[7];
  const float* coef_qk    = (const float*)d_in[8];
  const float* scale_base = (const float*)d_in[9];
  const float* scale_sp   = (const float*)d_in[10];
  const float* cqo        = (const float*)d_in[11];
  const float* lqw        = (const float*)d_in[12];
  const float* lqb        = (const float*)d_in[13];
  const float* lkw        = (const float*)d_in[14];
  const float* lkb        = (const float*)d_in[15];
  float* out = (float*)d_out;

  float* q5 = (float*)d_ws;                 // [6272,320]
  float* k5 = q5 + (size_t)BHP * 320;       // [6272,320]
  float* bq = k5 + (size_t)BHP * 320;       // [6272,320]  (reused as tabq)
  float* bk = bq + (size_t)BHP * 320;       // [6272,320]  (reused as tabk)
  float* aq = bk + (size_t)BHP * 320;       // [32,5,196]
  float* ak = aq + 32 * 5 * 196;            // [32,5,196]
  float2* tabq = (float2*)bq;               // [32*40*196] float2 (2 MB < 8 MB)
  float2* tabk = (float2*)bk;

  k1_lin_base<<<dim3(2 * BHP / 16), dim3(320), 0, stream>>>(
      q, k, lqw, lqb, lkw, lkb, base_w, q5, k5, bq, bk);
  k2_act<<<dim3(62720 / 4), dim3(256), 0, stream>>>(
      q5, bq, k5, bk, grid, coef_q, coef_k, scale_sp, scale_base, aq, ak);
  k2b_tab<<<dim3(980), dim3(256), 0, stream>>>(aq, ak, grid_outer, tabq, tabk);
  k3_outer<<<dim3(32 * 28), dim3(256), 0, stream>>>(tabq, tabk, coef_qk, cqo, out);
}

// Round 4
// 138.071 us; speedup vs baseline: 2.0422x; 1.1634x over previous
//
#include <hip/hip_runtime.h>
#include <math.h>

// Problem constants (B=4, H=8, P=196, D=64, NF=8, S=5)
#define BHP 6272   // B*H*P

// ---------------------------------------------------------------------------
// K1 (q and k merged): 16 rows per block, 320 threads (thread = output col o).
// ---------------------------------------------------------------------------
__global__ __launch_bounds__(320) void k1_lin_base(
    const float* __restrict__ qx, const float* __restrict__ kx,
    const float* __restrict__ Wq, const float* __restrict__ bq_,
    const float* __restrict__ Wk, const float* __restrict__ bk_,
    const float* __restrict__ BW,
    float* __restrict__ y5q, float* __restrict__ y5k,
    float* __restrict__ baseq, float* __restrict__ basek)
{
  const bool kside = blockIdx.x >= (BHP / 16);
  const float* x = kside ? kx : qx;
  const float* W = kside ? Wk : Wq;
  const float* bias = kside ? bk_ : bq_;
  float* y5 = kside ? y5k : y5q;
  float* basef = kside ? basek : baseq;
  const int r0 = (kside ? blockIdx.x - BHP / 16 : blockIdx.x) * 16;

  __shared__ float xs[16][64];    // 4 KB
  __shared__ float sy[16][320];   // 20 KB
  const int t = threadIdx.x;
  for (int idx = t; idx < 16 * 64; idx += 320)
    xs[idx >> 6][idx & 63] = x[(size_t)(r0 + (idx >> 6)) * 64 + (idx & 63)];
  __syncthreads();

  const int o = t;
  {
    const float* wrow = W + o * 64;
    float acc[16];
#pragma unroll
    for (int rr = 0; rr < 16; ++rr) acc[rr] = 0.f;
    for (int c = 0; c < 64; c += 4) {
      const float4 w4 = *reinterpret_cast<const float4*>(wrow + c);
#pragma unroll
      for (int rr = 0; rr < 16; ++rr) {
        const float4 x4 = *reinterpret_cast<const float4*>(&xs[rr][c]);
        acc[rr] += x4.x * w4.x + x4.y * w4.y + x4.z * w4.z + x4.w * w4.w;
      }
    }
    const float bb = bias[o];
#pragma unroll
    for (int rr = 0; rr < 16; ++rr) {
      const float y = acc[rr] + bb;
      y5[(size_t)(r0 + rr) * 320 + o] = y;
      sy[rr][o] = y / (1.f + __expf(-y));   // silu
    }
  }
  __syncthreads();
  {
    const int s = o >> 6, d = o & 63;
    const float* brow = BW + d * 64;
    float acc[16];
#pragma unroll
    for (int rr = 0; rr < 16; ++rr) acc[rr] = 0.f;
    for (int c = 0; c < 64; c += 4) {
      const float4 w4 = *reinterpret_cast<const float4*>(brow + c);
#pragma unroll
      for (int rr = 0; rr < 16; ++rr) {
        const float4 x4 = *reinterpret_cast<const float4*>(&sy[rr][s * 64 + c]);
        acc[rr] += x4.x * w4.x + x4.y * w4.y + x4.z * w4.z + x4.w * w4.w;
      }
    }
#pragma unroll
    for (int rr = 0; rr < 16; ++rr)
      basef[(size_t)(r0 + rr) * 320 + o] = acc[rr];
  }
}

// ---------------------------------------------------------------------------
// K2 (q/k merged + table gen fused): one wave per (side, bh, s2, p2); lane=d.
//   coef staged in LDS [m][d] (pad 65), incremental j/40 div, then the
//   sigmoid-sum is butterfly-reduced and lanes 0..7 write the sin/cos table.
// ---------------------------------------------------------------------------
__global__ __launch_bounds__(1024) void k2_act(
    const float* __restrict__ y5q, const float* __restrict__ bq,
    const float* __restrict__ y5k, const float* __restrict__ bk,
    const float* __restrict__ gridI, const float* __restrict__ gridO,
    const float* __restrict__ cq, const float* __restrict__ ck,
    const float* __restrict__ ssp, const float* __restrict__ sbase,
    float2* __restrict__ tq, float2* __restrict__ tk)
{
  __shared__ float cl[40][65];   // 10.2 KB, coef as [m][d], pad 65
  __shared__ float gli[40], glo[40];
  const int t = threadIdx.x;
  const int wave = t >> 6, lane = t & 63;
  const int gi = blockIdx.x * 16 + wave;       // [0, 62720); side-uniform/block
  const bool kside = gi >= 31360;
  const int idx = kside ? gi - 31360 : gi;

  {
    const float* coef = kside ? ck : cq;       // uniform within block
    for (int e = t; e < 2560; e += 1024) {
      const int d = e / 40, r = e % 40;        // coef flat = d*40 + f*5 + s
      const int f = r / 5, s = r % 5;
      cl[s * 8 + f][d] = coef[e];              // coalesced read
    }
    if (t < 40) { gli[t] = gridI[t]; glo[t] = gridO[t]; }
  }
  __syncthreads();

  const int p2 = idx % 196;
  const int s2 = (idx / 196) % 5;
  const int bh = idx / 980;
  const int h = bh & 7;
  const int d = lane;
  const int i0 = s2 * 196 + p2;
  const float* y5 = kside ? y5k : y5q;
  const float* basef = kside ? bk : bq;
  const float basev =
      basef[(size_t)(bh * 196 + i0 / 5) * 320 + (i0 % 5) * 64 + d];

  const int j0 = s2 * 1568 + p2;
  int p = j0 / 40;
  int m = j0 % 40;
  const float* y5b = y5 + (size_t)bh * 196 * 320 + d;
  float fv = 0.f;
#pragma unroll
  for (int f2 = 0; f2 < 8; ++f2) {
    const float g = gli[m];                        // LDS broadcast
    const float qv = y5b[p * 320 + (m >> 3) * 64]; // coalesced global
    fv = fmaf(__sinf(g * qv), cl[m][d], fv);       // LDS conflict-free
    p += 4; m += 36;
    if (m >= 40) { m -= 40; p += 1; }              // j += 196 carry
  }
  const int so = ((h * 5 + s2) * 196 + p2) * 64 + d;
  const float v = fv * ssp[so] + basev * sbase[so];
  float sg = 1.f / (1.f + __expf(-v));
#pragma unroll
  for (int off = 32; off > 0; off >>= 1) sg += __shfl_xor(sg, off);
  // every lane now holds a = sum_d sigmoid(...); fill the outer-basis table
  if (lane < 8) {
    const int mm = s2 * 8 + lane;
    float sv, cv;
    sincosf(glo[mm] * sg, &sv, &cv);     // accurate: args up to ~2600 rad
    float2* tab = kside ? tk : tq;
    tab[bh * 7840 + mm * 196 + p2] = make_float2(sv, cv);
  }
}

// ---------------------------------------------------------------------------
// K3: block = (bh, i-tile of 7). tk row in registers (reused over 7 rows);
// cqk row i staged coalesced into LDS (pad 48); tq rows preloaded once.
//   sin(g(aq+ak)) = sin(g aq)cos(g ak) + cos(g aq)sin(g ak)
// ---------------------------------------------------------------------------
__global__ __launch_bounds__(256) void k3_outer(
    const float2* __restrict__ tq, const float2* __restrict__ tk,
    const float* __restrict__ cqk, const float* __restrict__ cqo,
    float* __restrict__ out)
{
  const int bh = blockIdx.x / 28;
  const int it0 = (blockIdx.x % 28) * 7;
  const int t = threadIdx.x;
  const int j = t;
  const bool act = j < 196;
  __shared__ float cks[196][48];        // 36.75 KB (pad 48: 2-way-free reads)
  __shared__ float2 sqs[7][40];         // 2.24 KB
  __shared__ float redm[4], reds[4];

  for (int e = t; e < 280; e += 256) {
    const int ii = e / 40, mm = e % 40;
    sqs[ii][mm] = tq[bh * 7840 + mm * 196 + (it0 + ii)];
  }
  float2 tkv[40];
  if (act) {
    const float2* tkp = tk + bh * 7840 + j;
#pragma unroll
    for (int mm = 0; mm < 40; ++mm) tkv[mm] = tkp[mm * 196];  // coalesced
  }
  __syncthreads();

  for (int ii = 0; ii < 7; ++ii) {
    const int i = it0 + ii;
    // stage cqk row i (196*40 floats) coalesced -> LDS
    {
      const float4* src =
          reinterpret_cast<const float4*>(cqk + (size_t)i * 196 * 40);
      for (int e = t; e < 1960; e += 256) {
        const float4 v = src[e];
        const int jj = e / 10, uu = (e % 10) * 4;   // 40%4==0: no straddle
        *reinterpret_cast<float4*>(&cks[jj][uu]) = v;
      }
    }
    __syncthreads();

    float fval = -INFINITY;
    if (act) {
      float fj = 0.f;
#pragma unroll
      for (int s = 0; s < 5; ++s) {
        float t0 = 0.f;
#pragma unroll
        for (int f = 0; f < 8; ++f) {
          const int mm = s * 8 + f;
          const float2 kv = tkv[mm];
          const float2 sv = sqs[ii][mm];
          t0 = fmaf(sv.x * kv.y + sv.y * kv.x, cks[j][f * 5 + s], t0);
        }
        fj = fmaf(t0, cqo[(s * 196 + i) * 196 + j], fj);
      }
      fval = fj;
    }
    float mx = fval;
#pragma unroll
    for (int off = 32; off > 0; off >>= 1) mx = fmaxf(mx, __shfl_xor(mx, off));
    if ((t & 63) == 0) redm[t >> 6] = mx;
    __syncthreads();
    mx = fmaxf(fmaxf(redm[0], redm[1]), fmaxf(redm[2], redm[3]));
    const float e = act ? __expf(fval - mx) : 0.f;
    float ss = e;
#pragma unroll
    for (int off = 32; off > 0; off >>= 1) ss += __shfl_xor(ss, off);
    if ((t & 63) == 0) reds[t >> 6] = ss;
    __syncthreads();
    const float tot = reds[0] + reds[1] + reds[2] + reds[3];
    if (act) out[((size_t)(bh * 196 + i)) * 196 + j] = e / tot;
    // next-ii cks writes are safe: all reads precede the redm sync above
  }
}

// ---------------------------------------------------------------------------
extern "C" void kernel_launch(void* const* d_in, const int* in_sizes, int n_in,
                              void* d_out, int out_size, void* d_ws, size_t ws_size,
                              hipStream_t stream) {
  const float* q          = (const float*)d_in[0];
  const float* k          = (const float*)d_in[1];
  const float* grid       = (const float*)d_in[3];
  const float* grid_outer = (const float*)d_in[4];
  const float* base_w     = (const float*)d_in[5];
  const float* coef_q     = (const float*)d_in[6];
  const float* coef_k     = (const float*)d_in[7];
  const float* coef_qk    = (const float*)d_in[8];
  const float* scale_base = (const float*)d_in[9];
  const float* scale_sp   = (const float*)d_in[10];
  const float* cqo        = (const float*)d_in[11];
  const float* lqw        = (const float*)d_in[12];
  const float* lqb        = (const float*)d_in[13];
  const float* lkw        = (const float*)d_in[14];
  const float* lkb        = (const float*)d_in[15];
  float* out = (float*)d_out;

  float* q5 = (float*)d_ws;                 // [6272,320]
  float* k5 = q5 + (size_t)BHP * 320;       // [6272,320]
  float* bq = k5 + (size_t)BHP * 320;       // [6272,320]  (reused as tabq)
  float* bk = bq + (size_t)BHP * 320;       // [6272,320]  (reused as tabk)
  float2* tabq = (float2*)(bk + (size_t)BHP * 320);   // [32*40*196] float2
  float2* tabk = tabq + 32 * 40 * 196;

  k1_lin_base<<<dim3(2 * BHP / 16), dim3(320), 0, stream>>>(
      q, k, lqw, lqb, lkw, lkb, base_w, q5, k5, bq, bk);
  k2_act<<<dim3(62720 / 16), dim3(1024), 0, stream>>>(
      q5, bq, k5, bk, grid, grid_outer, coef_q, coef_k,
      scale_sp, scale_base, tabq, tabk);
  k3_outer<<<dim3(32 * 28), dim3(256), 0, stream>>>(tabq, tabk, coef_qk, cqo, out);
}